// Round 15
// baseline (7554.475 us; speedup 1.0000x reference)
//
#include <hip/hip_runtime.h>
#include <hip/hip_bf16.h>
#include <math.h>

#define SEQL 2048
#define EDIM 256
#define HID 256
#define G4 1024
#define HCAT 512
#define TT 11
#define START_TAG 9
#define STOP_TAG 10
#define NEGV -10000.0f
#define ALPHA_LR 0.2f
#define VCH 64
#define VCS 32
#define NU 16      // units per LSTM block
#define NBLK 16    // blocks per direction

__device__ __forceinline__ float sigf(float x) { return 1.0f / (1.0f + __expf(-x)); }
__device__ __forceinline__ float tanhfast(float x) { return 2.0f / (1.0f + __expf(-2.0f * x)) - 1.0f; }
__device__ __forceinline__ unsigned int bfp(float f) {
    union { float f; unsigned int u; } c; c.f = f;
    return (c.u + 0x7FFFu + ((c.u >> 16) & 1u)) >> 16;   // RNE bf16 (hi16)
}
__device__ __forceinline__ float bflo(unsigned int u) { return __uint_as_float(u << 16); }
__device__ __forceinline__ float bfhi(unsigned int u) { return __uint_as_float(u & 0xFFFF0000u); }

// ---------------- embedding gather ----------------
__global__ void embed_k(const int* __restrict__ sent, const float* __restrict__ emb,
                        float* __restrict__ x) {
    int idx = blockIdx.x * 256 + threadIdx.x;
    int t = idx >> 8, e = idx & 255;
    x[idx] = emb[(size_t)sent[t] * EDIM + e];
}

// ---------------- GEMM: C[M,N] = A[M,K] * B[N,K]^T + bias ----------------
__global__ __launch_bounds__(256) void gemm_nt(const float* __restrict__ A,
                                               const float* __restrict__ B,
                                               const float* __restrict__ bias,
                                               float* __restrict__ C,
                                               int M, int N, int K) {
    __shared__ float As[16][68];
    __shared__ float Bs[16][68];
    int tid = threadIdx.x;
    int tx = tid & 15, ty = tid >> 4;
    int m0 = blockIdx.y * 64, n0 = blockIdx.x * 64;
    int lr = tid >> 2;
    int lc = (tid & 3) * 4;
    float acc[4][4] = {};
    for (int k0 = 0; k0 < K; k0 += 16) {
        float4 av = *(const float4*)(A + (size_t)(m0 + lr) * K + k0 + lc);
        float4 bv = make_float4(0.f, 0.f, 0.f, 0.f);
        if (n0 + lr < N) bv = *(const float4*)(B + (size_t)(n0 + lr) * K + k0 + lc);
        As[lc + 0][lr] = av.x; As[lc + 1][lr] = av.y; As[lc + 2][lr] = av.z; As[lc + 3][lr] = av.w;
        Bs[lc + 0][lr] = bv.x; Bs[lc + 1][lr] = bv.y; Bs[lc + 2][lr] = bv.z; Bs[lc + 3][lr] = bv.w;
        __syncthreads();
#pragma unroll
        for (int kk = 0; kk < 16; ++kk) {
            float4 a4 = *(const float4*)&As[kk][ty * 4];
            float4 b4 = *(const float4*)&Bs[kk][tx * 4];
            float aa[4] = {a4.x, a4.y, a4.z, a4.w};
            float bb[4] = {b4.x, b4.y, b4.z, b4.w};
#pragma unroll
            for (int i = 0; i < 4; ++i)
#pragma unroll
                for (int j = 0; j < 4; ++j) acc[i][j] += aa[i] * bb[j];
        }
        __syncthreads();
    }
#pragma unroll
    for (int i = 0; i < 4; ++i) {
        int m = m0 + ty * 4 + i;
#pragma unroll
        for (int j = 0; j < 4; ++j) {
            int n = n0 + tx * 4 + j;
            if (n < N) {
                float v = acc[i][j];
                if (bias) v += bias[n];
                C[(size_t)m * N + n] = v;
            }
        }
    }
}

// ---------------- K-split GEMM partials: Cpart[kz] = A[:,kz-slice] * B[kz-slice,:] ----
__global__ __launch_bounds__(256) void gemm_nn_ks(const float* __restrict__ A,
                                                  const float* __restrict__ B,
                                                  float* __restrict__ Cpart,
                                                  int M, int N, int K4) {
    __shared__ float As[16][68];
    __shared__ float Bs[16][68];
    int tid = threadIdx.x;
    int tx = tid & 15, ty = tid >> 4;
    int m0 = blockIdx.y * 64, n0 = blockIdx.x * 64;
    int kz = blockIdx.z;
    int K = (int)gridDim.z * K4;
    int kbeg = kz * K4, kend = kbeg + K4;
    int lr = tid >> 2;
    int lc = (tid & 3) * 4;
    int br = tid >> 4;
    int bc = (tid & 15) * 4;
    float acc[4][4] = {};
    for (int k0 = kbeg; k0 < kend; k0 += 16) {
        float4 av = *(const float4*)(A + (size_t)(m0 + lr) * K + k0 + lc);
        float4 bv = *(const float4*)(B + (size_t)(k0 + br) * N + n0 + bc);
        As[lc + 0][lr] = av.x; As[lc + 1][lr] = av.y; As[lc + 2][lr] = av.z; As[lc + 3][lr] = av.w;
        *(float4*)&Bs[br][bc] = bv;
        __syncthreads();
#pragma unroll
        for (int kk = 0; kk < 16; ++kk) {
            float4 a4 = *(const float4*)&As[kk][ty * 4];
            float4 b4 = *(const float4*)&Bs[kk][tx * 4];
            float aa[4] = {a4.x, a4.y, a4.z, a4.w};
            float bb[4] = {b4.x, b4.y, b4.z, b4.w};
#pragma unroll
            for (int i = 0; i < 4; ++i)
#pragma unroll
                for (int j = 0; j < 4; ++j) acc[i][j] += aa[i] * bb[j];
        }
        __syncthreads();
    }
    float* Cz = Cpart + (size_t)kz * M * N;
#pragma unroll
    for (int i = 0; i < 4; ++i) {
        int m = m0 + ty * 4 + i;
#pragma unroll
        for (int j = 0; j < 4; ++j) {
            int n = n0 + tx * 4 + j;
            Cz[(size_t)m * N + n] = acc[i][j];
        }
    }
}

// ---------------- finishers ----------------
__global__ void attn_fin(const float* __restrict__ Cp, const float* __restrict__ Zr,
                         float* __restrict__ C, int MN, int N) {
    int idx = blockIdx.x * 256 + threadIdx.x;
    float v = Cp[idx] + Cp[MN + idx] + Cp[2 * MN + idx] + Cp[3 * MN + idx];
    v /= Zr[idx / N];
    C[idx] = v > 0.f ? v : (__expf(v) - 1.f);
}

__global__ void sum4_fin(const float* __restrict__ Cp, float* __restrict__ C, int MN) {
    int idx = blockIdx.x * 256 + threadIdx.x;
    C[idx] = Cp[idx] + Cp[MN + idx] + Cp[2 * MN + idx] + Cp[3 * MN + idx];
}

// ---------------- BiLSTM recurrent scan: XCC-verified roles + L2-fast exchange ------
// Grid 256. Each block reads its physical XCD (s_getreg XCC_ID), claims a role slot
// in census[xcd]; all blocks rendezvous (census total spin -- all 256 co-resident:
// 4 blocks/CU capacity). Assignment (computed identically by all blocks from final
// census): dir0 = roles 0..15 on most-populated XCD (max >= 32 by pigeonhole),
// dir1 = roles 0..15 on runner-up XCD if it has >=16, else roles 16..31 of the first.
// => same-dir partners PROVABLY share an L2. Exchange: publisher (wave0 lanes 0..15,
// even lanes store 64-bit packed pairs) dual-store = plain volatile (L2 path) +
// agent-atomic (LLC guarantee); pollers (waves 1..2, one 64-bit pair each) spin on
// plain volatile with 1-in-8 agent-atomic fallback -> live under ANY placement.
// Word = (bf16(h)<<16 | steptag); halves self-tagged (tearing harmless). Parity
// double-buffer; ABA-safe by value dependence; pub+census memset per launch.
__global__ __launch_bounds__(256) void lstm_lds(const float* __restrict__ xin_f,
                                                const float* __restrict__ xin_b,
                                                const float* __restrict__ whh_f,
                                                const float* __restrict__ whh_b,
                                                const float* __restrict__ hc,
                                                float* __restrict__ out,
                                                unsigned int* pubu, int* census,
                                                int tagbase) {
    int tid = threadIdx.x;
    __shared__ int role_s, dirb_s;
    __shared__ unsigned xcc_s;

    if (tid == 0) {
        unsigned xcc;
        asm volatile("s_getreg_b32 %0, hwreg(HW_REG_XCC_ID)" : "=s"(xcc));
        xcc &= 7u;
        xcc_s = xcc;
        role_s = atomicAdd(&census[xcc], 1);
        atomicAdd(&census[8], 1);                      // census total
        // rendezvous: all 256 blocks co-resident (LDS 35.8KB -> 4 blk/CU, cap 1024)
        while (__hip_atomic_load(&census[8], __ATOMIC_ACQUIRE,
                                 __HIP_MEMORY_SCOPE_AGENT) < (int)gridDim.x) {}
        int cnt[8];
        for (int i = 0; i < 8; ++i)
            cnt[i] = __hip_atomic_load(&census[i], __ATOMIC_RELAXED,
                                       __HIP_MEMORY_SCOPE_AGENT);
        int xA = 0;
        for (int i = 1; i < 8; ++i) if (cnt[i] > cnt[xA]) xA = i;
        int xB = (xA == 0) ? 1 : 0;
        for (int i = 0; i < 8; ++i)
            if (i != xA && cnt[i] > cnt[xB]) xB = i;
        int dir = -1, b = -1;
        int xcb = (int)xcc_s, roleb = role_s;
        if (xcb == xA && roleb < 16) { dir = 0; b = roleb; }
        if (cnt[xB] >= 16) {
            if (xcb == xB && roleb < 16) { dir = 1; b = roleb; }
        } else {
            if (xcb == xA && roleb >= 16 && roleb < 32) { dir = 1; b = roleb - 16; }
        }
        dirb_s = (dir < 0) ? -1 : (dir * 16 + b);
    }
    __syncthreads();
    if (dirb_s < 0) return;                             // non-participant blocks exit
    int dir = dirb_s >> 4;
    int b = dirb_s & 15;

    const float* xin = dir ? xin_b : xin_f;
    const float* whh = dir ? whh_b : whh_f;

    __shared__ uint4 W4[2048];                    // 32KB bf16 weights
    __shared__ __align__(16) float hbuf[256];     // current h (fp32/own, bf16/partner)
    __shared__ float zp[512];                     // partial dots [k8][row]

    // ---- one-time weight staging, packed for wave-linear consumption ----
    for (int idx = tid; idx < 2048; idx += 256) {
        int wave = idx >> 9;
        int i = (idx >> 6) & 7;
        int l = idx & 63;
        int towner = wave * 64 + l;
        int rp = towner & 31;
        int k8 = towner >> 5;
        int rloc = 2 * rp + (i >> 2);
        int ii = i & 3;
        int g = rloc >> 4, j = rloc & 15;
        const float* wr = whh + (size_t)(g * HID + b * NU + j) * HID + k8 * 32 + ii * 8;
        uint4 v;
        v.x = bfp(wr[0]) | (bfp(wr[1]) << 16);
        v.y = bfp(wr[2]) | (bfp(wr[3]) << 16);
        v.z = bfp(wr[4]) | (bfp(wr[5]) << 16);
        v.w = bfp(wr[6]) | (bfp(wr[7]) << 16);
        W4[wave * 512 + i * 64 + l] = v;
    }

    if (tid < 256) hbuf[tid] = hc[dir * 512 + tid];
    float c = 0.f;
    float xq0 = 0.f, xq1 = 0.f, xq2 = 0.f, xq3 = 0.f;
    if (tid < 16) {
        c = hc[dir * 512 + 256 + b * NU + tid];
        int t0 = dir ? (SEQL - 1) : 0;
        const float* xr = xin + (size_t)t0 * G4 + b * NU + tid;
        xq0 = xr[0]; xq1 = xr[256]; xq2 = xr[512]; xq3 = xr[768];
    }
    __syncthreads();

    int rp = tid & 31;
    int k8 = tid >> 5;
    int wbase = (tid >> 6) * 512 + (tid & 63);
    const float4* hb4 = (const float4*)hbuf;

    // poller mapping: tid 64..183 -> one of 120 partner unit-pairs
    int ppair = tid - 64;
    int upair = (ppair < b * 8) ? ppair : ppair + 8;

    for (int s = 0; s < SEQL; ++s) {
        // ---- dot phase: all 256 threads ----
        float acc0 = 0.f, acc1 = 0.f;
#pragma unroll
        for (int i = 0; i < 4; ++i) {
            uint4 w0 = W4[wbase + i * 64];
            uint4 w1 = W4[wbase + (i + 4) * 64];
            float4 hA = hb4[k8 * 8 + i * 2];
            float4 hB = hb4[k8 * 8 + i * 2 + 1];
            acc0 += bflo(w0.x) * hA.x + bfhi(w0.x) * hA.y + bflo(w0.y) * hA.z + bfhi(w0.y) * hA.w
                  + bflo(w0.z) * hB.x + bfhi(w0.z) * hB.y + bflo(w0.w) * hB.z + bfhi(w0.w) * hB.w;
            acc1 += bflo(w1.x) * hA.x + bfhi(w1.x) * hA.y + bflo(w1.y) * hA.z + bfhi(w1.y) * hA.w
                  + bflo(w1.z) * hB.x + bfhi(w1.z) * hB.y + bflo(w1.w) * hB.z + bfhi(w1.w) * hB.w;
        }
        zp[k8 * 64 + 2 * rp] = acc0;
        zp[k8 * 64 + 2 * rp + 1] = acc1;
        __syncthreads();

        int t = dir ? (SEQL - 1 - s) : s;
        unsigned int etag = (unsigned int)(tagbase + s + 1) & 0xFFFFu;
        unsigned int* slot = pubu + (((s + 1) & 1) * 2 + dir) * 256;

        if (tid < 16) {
            // ---- gate phase + packed dual publish (wave 0) ----
            float zi = xq0, zf = xq1, zg = xq2, zo = xq3;
#pragma unroll
            for (int q = 0; q < 8; ++q) {
                zi += zp[q * 64 + tid];
                zf += zp[q * 64 + 16 + tid];
                zg += zp[q * 64 + 32 + tid];
                zo += zp[q * 64 + 48 + tid];
            }
            float ig = sigf(zi), fg = sigf(zf), gt = tanhfast(zg), og = sigf(zo);
            c = fg * c + ig * gt;
            float hn = og * tanhfast(c);
            hbuf[b * NU + tid] = hn;
            unsigned int word = (bfp(hn) << 16) | etag;
            unsigned int wnext = __shfl_down(word, 1, 64);
            if ((tid & 1) == 0) {
                unsigned long long w64 = (unsigned long long)word |
                                         ((unsigned long long)wnext << 32);
                *(volatile unsigned long long*)&slot[b * NU + tid] = w64;   // L2 path
                __hip_atomic_store((unsigned long long*)&slot[b * NU + tid], w64,
                                   __ATOMIC_RELAXED, __HIP_MEMORY_SCOPE_AGENT); // LLC
            }
            out[(size_t)t * HCAT + dir * HID + b * NU + tid] = hn;
            // prefetch next x
            if (s + 1 < SEQL) {
                int tn = dir ? (SEQL - 2 - s) : (s + 1);
                const float* xr = xin + (size_t)tn * G4 + b * NU + tid;
                xq0 = xr[0]; xq1 = xr[256]; xq2 = xr[512]; xq3 = xr[768];
            }
        } else if (tid >= 64 && tid < 184 && s + 1 < SEQL) {
            // ---- poll phase: waves 1..2, one 64-bit pair each ----
            unsigned long long v; int it = 0;
            for (;;) {
                v = *(volatile const unsigned long long*)&slot[upair * 2];   // L2 path
                if ((unsigned int)(v & 0xFFFFu) == etag &&
                    (unsigned int)((v >> 32) & 0xFFFFu) == etag) break;
                if ((++it & 7) == 0) {
                    v = __hip_atomic_load((unsigned long long*)&slot[upair * 2],
                                          __ATOMIC_RELAXED, __HIP_MEMORY_SCOPE_AGENT);
                    if ((unsigned int)(v & 0xFFFFu) == etag &&
                        (unsigned int)((v >> 32) & 0xFFFFu) == etag) break;
                }
            }
            hbuf[upair * 2]     = bfhi((unsigned int)v);
            hbuf[upair * 2 + 1] = bfhi((unsigned int)(v >> 32));
        }
        __syncthreads();
    }
}

// ---------------- GAT helpers ----------------
__global__ void gat_scores(const float* __restrict__ Wh, const float* __restrict__ a,
                           float* __restrict__ s1, float* __restrict__ s2) {
    int i = blockIdx.x;
    int lane = threadIdx.x;  // 64
    const float* rowp = Wh + (size_t)i * HCAT;
    float p1 = 0.f, p2 = 0.f;
    for (int k = lane; k < HCAT; k += 64) {
        float w = rowp[k];
        p1 += w * a[k];
        p2 += w * a[HCAT + k];
    }
    for (int off = 32; off; off >>= 1) {
        p1 += __shfl_down(p1, off, 64);
        p2 += __shfl_down(p2, off, 64);
    }
    if (lane == 0) { s1[i] = p1; s2[i] = p2; }
}

__global__ void reduce_max_k(const float* __restrict__ s2, float* __restrict__ outv) {
    __shared__ float red[256];
    int tid = threadIdx.x;
    float m = -INFINITY;
    for (int k = tid; k < SEQL; k += 256) m = fmaxf(m, s2[k]);
    red[tid] = m;
    __syncthreads();
    for (int off = 128; off; off >>= 1) {
        if (tid < off) red[tid] = fmaxf(red[tid], red[tid + off]);
        __syncthreads();
    }
    if (tid == 0) outv[0] = red[0];
}

__global__ void gat_p(const float* __restrict__ s1, const float* __restrict__ s2,
                      const float* __restrict__ s2m, float* __restrict__ P,
                      float* __restrict__ Z) {
    int i = blockIdx.x;
    int tid = threadIdx.x;  // 256
    float base = s1[i];
    float m = base + s2m[0];
    m = m > 0.f ? m : ALPHA_LR * m;  // leaky_relu monotonic -> exact row max
    float zs = 0.f;
    for (int jj = tid; jj < SEQL; jj += 256) {
        float e = base + s2[jj];
        e = e > 0.f ? e : ALPHA_LR * e;
        float p = __expf(e - m);
        P[(size_t)i * SEQL + jj] = p;
        zs += p;
    }
    __shared__ float red[256];
    red[tid] = zs;
    __syncthreads();
    for (int off = 128; off; off >>= 1) {
        if (tid < off) red[tid] += red[tid + off];
        __syncthreads();
    }
    if (tid == 0) Z[i] = red[0];
}

// ---------------- Viterbi (max-plus parallel scan) ----------------
__global__ void vit_chunkA(const float* __restrict__ feats, const float* __restrict__ trans,
                           float* __restrict__ chunkA) {
    int c = blockIdx.x;
    int tid = threadIdx.x;  // 128
    __shared__ float Acur[121], tr[121];
    if (tid < 121) tr[tid] = trans[tid];
    __syncthreads();
    int n = tid / 11, p = tid % 11;
    int t0 = c * VCS;
    if (tid < 121) Acur[tid] = tr[tid] + feats[t0 * TT + n];
    __syncthreads();
    for (int t = t0 + 1; t < t0 + VCS; ++t) {
        float v = -INFINITY;
        if (tid < 121) {
            float ft = feats[t * TT + n];
#pragma unroll
            for (int k = 0; k < 11; ++k) v = fmaxf(v, tr[n * 11 + k] + Acur[k * 11 + p]);
            v += ft;
        }
        __syncthreads();
        if (tid < 121) Acur[tid] = v;
        __syncthreads();
    }
    if (tid < 121) chunkA[c * 121 + tid] = Acur[tid];
}

__global__ void vit_prefix(const float* __restrict__ chunkA, float* __restrict__ fvstart) {
    int tid = threadIdx.x;  // 128
    __shared__ float fv[11];
    if (tid < 11) fv[tid] = (tid == START_TAG) ? 0.f : NEGV;
    __syncthreads();
    if (tid < 11) fvstart[tid] = fv[tid];
    for (int c = 0; c < VCH; ++c) {
        float v = -INFINITY;
        if (tid < 11) {
            for (int p = 0; p < 11; ++p) v = fmaxf(v, chunkA[c * 121 + tid * 11 + p] + fv[p]);
        }
        __syncthreads();
        if (tid < 11) { fv[tid] = v; fvstart[(c + 1) * TT + tid] = v; }
        __syncthreads();
    }
}

__global__ void vit_chunkC(const float* __restrict__ feats, const float* __restrict__ trans,
                           const float* __restrict__ fvstart, int* __restrict__ bp,
                           float* __restrict__ fvfinal) {
    int c = blockIdx.x;
    int tid = threadIdx.x;  // 128
    __shared__ float fv[11], tr[121], sc[121], mx[11];
    if (tid < 121) tr[tid] = trans[tid];
    if (tid < 11) fv[tid] = fvstart[c * TT + tid];
    __syncthreads();
    int t0 = c * VCS;
    for (int t = t0; t < t0 + VCS; ++t) {
        if (tid < 121) sc[tid] = fv[tid % 11] + tr[tid];
        __syncthreads();
        if (tid < 11) {
            float best = -INFINITY;
            int bi = 0;
            for (int k = 0; k < 11; ++k) {
                float v = sc[tid * 11 + k];
                if (v > best) { best = v; bi = k; }
            }
            bp[t * TT + tid] = bi;
            mx[tid] = best + feats[t * TT + tid];
        }
        __syncthreads();
        if (tid < 11) fv[tid] = mx[tid];
        __syncthreads();
    }
    if (c == VCH - 1 && tid < 11) fvfinal[tid] = fv[tid];
}

__global__ __launch_bounds__(1024) void vit_back(const int* __restrict__ bp,
                                                 const float* __restrict__ fvfinal,
                                                 const float* __restrict__ trans,
                                                 float* __restrict__ outp) {
    __shared__ unsigned char bufA[SEQL * TT];
    __shared__ unsigned char bufB[SEQL * TT];
    __shared__ int bestIdx;
    int tid = threadIdx.x;
    for (int idx = tid; idx < SEQL * TT; idx += 1024) {
        int t = idx / TT, n = idx - t * TT;
        bufA[idx] = (t < SEQL - 1) ? (unsigned char)bp[(t + 1) * TT + n] : (unsigned char)n;
    }
    __syncthreads();
    unsigned char* a = bufA;
    unsigned char* b = bufB;
    for (int len = 1; len < SEQL - 1; len <<= 1) {
        for (int idx = tid; idx < SEQL * TT; idx += 1024) {
            int t = idx / TT, n = idx - t * TT;
            int m = (t + len <= SEQL - 1) ? (int)a[(t + len) * TT + n] : n;
            b[t * TT + n] = a[t * TT + m];
        }
        __syncthreads();
        unsigned char* tmp = a; a = b; b = tmp;
        __syncthreads();
    }
    if (tid == 0) {
        float bs = -INFINITY;
        int bi = 0;
        for (int p = 0; p < 11; ++p) {
            float v = fvfinal[p] + trans[STOP_TAG * 11 + p];
            if (v > bs) { bs = v; bi = p; }
        }
        outp[0] = bs;
        bestIdx = bi;
    }
    __syncthreads();
    int best = bestIdx;
    for (int t = tid; t < SEQL; t += 1024) outp[1 + t] = (float)a[t * TT + best];
}

// ---------------- host launcher ----------------
extern "C" void kernel_launch(void* const* d_in, const int* in_sizes, int n_in,
                              void* d_out, int out_size, void* d_ws, size_t ws_size,
                              hipStream_t stream) {
    const int* sent = (const int*)d_in[0];
    const float* emb = (const float*)d_in[1];
    const float* w1f = (const float*)d_in[2];
    const float* u1f = (const float*)d_in[3];
    const float* b1f = (const float*)d_in[4];
    const float* w1b = (const float*)d_in[5];
    const float* u1b = (const float*)d_in[6];
    const float* b1b = (const float*)d_in[7];
    const float* hc1 = (const float*)d_in[8];
    const float* g1W = (const float*)d_in[9];
    const float* g1a = (const float*)d_in[10];
    const float* g2W = (const float*)d_in[11];
    const float* g2a = (const float*)d_in[12];
    const float* w2f = (const float*)d_in[13];
    const float* u2f = (const float*)d_in[14];
    const float* b2f = (const float*)d_in[15];
    const float* w2b = (const float*)d_in[16];
    const float* u2b = (const float*)d_in[17];
    const float* b2b = (const float*)d_in[18];
    const float* hc2 = (const float*)d_in[19];
    const float* wtag = (const float*)d_in[20];
    const float* btag = (const float*)d_in[21];
    const float* trans = (const float*)d_in[22];

    float* ws = (float*)d_ws;
    float* x = ws;                      // 524288
    float* R1 = x + 524288;             // 4194304 floats (xin_f+xin_b | P)
    float* xin_f = R1;
    float* xin_b = R1 + 2097152;
    float* P = R1;
    float* h1cat = R1 + 4194304;        // 1048576 (h1cat | g2)
    float* Wh = h1cat + 1048576;        // 1048576
    float* g1 = Wh + 1048576;           // 1048576 (g1 | h2cat)
    float* s1 = g1 + 1048576;           // 2048
    float* s2 = s1 + 2048;              // 2048
    float* Zr = s2 + 2048;              // 2048
    float* s2m = Zr + 2048;             // 16
    unsigned int* pub = (unsigned int*)(s2m + 16);  // 1024 u32 (8B-aligned)
    int* census1 = (int*)(pub + 1024);              // 16 ints
    int* census2 = census1 + 16;                    // 16 ints
    float* feats = (float*)(census2 + 16);          // 22528
    float* chA = feats + 22528;         // 7744
    float* fvst = chA + 7744;           // 720
    float* fvfin = fvst + 720;          // 16
    int* bp = (int*)(fvfin + 16);       // 22528 ints
    float* Cpart = (float*)(bp + 22528); // 4x1048576 floats (16MB)

    hipMemsetAsync(pub, 0, (1024 + 32) * sizeof(unsigned int), stream);

    embed_k<<<SEQL, 256, 0, stream>>>(sent, emb, x);

    // BiLSTM 1 input projections
    gemm_nt<<<dim3(16, 32), 256, 0, stream>>>(x, w1f, b1f, xin_f, SEQL, G4, EDIM);
    gemm_nt<<<dim3(16, 32), 256, 0, stream>>>(x, w1b, b1b, xin_b, SEQL, G4, EDIM);
    lstm_lds<<<256, 256, 0, stream>>>(xin_f, xin_b, u1f, u1b, hc1, h1cat, pub, census1, 0);

    // GAT 1 (both GEMMs K-split x4 for occupancy)
    gemm_nn_ks<<<dim3(8, 32, 4), 256, 0, stream>>>(h1cat, g1W, Cpart, SEQL, HCAT, HCAT / 4);
    sum4_fin<<<4096, 256, 0, stream>>>(Cpart, Wh, SEQL * HCAT);
    gat_scores<<<SEQL, 64, 0, stream>>>(Wh, g1a, s1, s2);
    reduce_max_k<<<1, 256, 0, stream>>>(s2, s2m);
    gat_p<<<SEQL, 256, 0, stream>>>(s1, s2, s2m, P, Zr);
    gemm_nn_ks<<<dim3(8, 32, 4), 256, 0, stream>>>(P, Wh, Cpart, SEQL, HCAT, SEQL / 4);
    attn_fin<<<4096, 256, 0, stream>>>(Cpart, Zr, g1, SEQL * HCAT, HCAT);

    // GAT 2
    gemm_nn_ks<<<dim3(8, 32, 4), 256, 0, stream>>>(g1, g2W, Cpart, SEQL, HCAT, HCAT / 4);
    sum4_fin<<<4096, 256, 0, stream>>>(Cpart, Wh, SEQL * HCAT);
    gat_scores<<<SEQL, 64, 0, stream>>>(Wh, g2a, s1, s2);
    reduce_max_k<<<1, 256, 0, stream>>>(s2, s2m);
    gat_p<<<SEQL, 256, 0, stream>>>(s1, s2, s2m, P, Zr);
    float* g2v = h1cat;  // reuse
    gemm_nn_ks<<<dim3(8, 32, 4), 256, 0, stream>>>(P, Wh, Cpart, SEQL, HCAT, SEQL / 4);
    attn_fin<<<4096, 256, 0, stream>>>(Cpart, Zr, g2v, SEQL * HCAT, HCAT);

    // BiLSTM 2
    gemm_nt<<<dim3(16, 32), 256, 0, stream>>>(g2v, w2f, b2f, xin_f, SEQL, G4, HCAT);
    gemm_nt<<<dim3(16, 32), 256, 0, stream>>>(g2v, w2b, b2b, xin_b, SEQL, G4, HCAT);
    float* h2cat = g1;  // reuse
    lstm_lds<<<256, 256, 0, stream>>>(xin_f, xin_b, u2f, u2b, hc2, h2cat, pub, census2, 2048);

    // tag projection + Viterbi
    gemm_nt<<<dim3(1, 32), 256, 0, stream>>>(h2cat, wtag, btag, feats, SEQL, TT, HCAT);
    vit_chunkA<<<VCH, 128, 0, stream>>>(feats, trans, chA);
    vit_prefix<<<1, 128, 0, stream>>>(chA, fvst);
    vit_chunkC<<<VCH, 128, 0, stream>>>(feats, trans, fvst, bp, fvfin);
    vit_back<<<1, 1024, 0, stream>>>(bp, fvfin, trans, (float*)d_out);
}

// Round 16
// 6508.294 us; speedup vs baseline: 1.1607x; 1.1607x over previous
//
#include <hip/hip_runtime.h>
#include <hip/hip_bf16.h>
#include <math.h>

#define SEQL 2048
#define EDIM 256
#define HID 256
#define G4 1024
#define HCAT 512
#define TT 11
#define START_TAG 9
#define STOP_TAG 10
#define NEGV -10000.0f
#define ALPHA_LR 0.2f
#define VCH 64
#define VCS 32
#define NU 16      // units per LSTM block
#define NBLK 16    // blocks per direction
#define HIDX(u) ((((u) >> 5) * 36) + ((u) & 31))   // padded hbuf index (36 floats/chunk)

__device__ __forceinline__ float sigf(float x) { return 1.0f / (1.0f + __expf(-x)); }
__device__ __forceinline__ float tanhfast(float x) { return 2.0f / (1.0f + __expf(-2.0f * x)) - 1.0f; }
__device__ __forceinline__ unsigned int bfp(float f) {
    union { float f; unsigned int u; } c; c.f = f;
    return (c.u + 0x7FFFu + ((c.u >> 16) & 1u)) >> 16;   // RNE bf16 (hi16)
}
__device__ __forceinline__ float bflo(unsigned int u) { return __uint_as_float(u << 16); }
__device__ __forceinline__ float bfhi(unsigned int u) { return __uint_as_float(u & 0xFFFF0000u); }

// ---------------- embedding gather ----------------
__global__ void embed_k(const int* __restrict__ sent, const float* __restrict__ emb,
                        float* __restrict__ x) {
    int idx = blockIdx.x * 256 + threadIdx.x;
    int t = idx >> 8, e = idx & 255;
    x[idx] = emb[(size_t)sent[t] * EDIM + e];
}

// ---------------- GEMM: C[M,N] = A[M,K] * B[N,K]^T + bias ----------------
__global__ __launch_bounds__(256) void gemm_nt(const float* __restrict__ A,
                                               const float* __restrict__ B,
                                               const float* __restrict__ bias,
                                               float* __restrict__ C,
                                               int M, int N, int K) {
    __shared__ float As[16][68];
    __shared__ float Bs[16][68];
    int tid = threadIdx.x;
    int tx = tid & 15, ty = tid >> 4;
    int m0 = blockIdx.y * 64, n0 = blockIdx.x * 64;
    int lr = tid >> 2;
    int lc = (tid & 3) * 4;
    float acc[4][4] = {};
    for (int k0 = 0; k0 < K; k0 += 16) {
        float4 av = *(const float4*)(A + (size_t)(m0 + lr) * K + k0 + lc);
        float4 bv = make_float4(0.f, 0.f, 0.f, 0.f);
        if (n0 + lr < N) bv = *(const float4*)(B + (size_t)(n0 + lr) * K + k0 + lc);
        As[lc + 0][lr] = av.x; As[lc + 1][lr] = av.y; As[lc + 2][lr] = av.z; As[lc + 3][lr] = av.w;
        Bs[lc + 0][lr] = bv.x; Bs[lc + 1][lr] = bv.y; Bs[lc + 2][lr] = bv.z; Bs[lc + 3][lr] = bv.w;
        __syncthreads();
#pragma unroll
        for (int kk = 0; kk < 16; ++kk) {
            float4 a4 = *(const float4*)&As[kk][ty * 4];
            float4 b4 = *(const float4*)&Bs[kk][tx * 4];
            float aa[4] = {a4.x, a4.y, a4.z, a4.w};
            float bb[4] = {b4.x, b4.y, b4.z, b4.w};
#pragma unroll
            for (int i = 0; i < 4; ++i)
#pragma unroll
                for (int j = 0; j < 4; ++j) acc[i][j] += aa[i] * bb[j];
        }
        __syncthreads();
    }
#pragma unroll
    for (int i = 0; i < 4; ++i) {
        int m = m0 + ty * 4 + i;
#pragma unroll
        for (int j = 0; j < 4; ++j) {
            int n = n0 + tx * 4 + j;
            if (n < N) {
                float v = acc[i][j];
                if (bias) v += bias[n];
                C[(size_t)m * N + n] = v;
            }
        }
    }
}

// ---------------- K-split GEMM partials: Cpart[kz] = A[:,kz-slice] * B[kz-slice,:] ----
__global__ __launch_bounds__(256) void gemm_nn_ks(const float* __restrict__ A,
                                                  const float* __restrict__ B,
                                                  float* __restrict__ Cpart,
                                                  int M, int N, int K4) {
    __shared__ float As[16][68];
    __shared__ float Bs[16][68];
    int tid = threadIdx.x;
    int tx = tid & 15, ty = tid >> 4;
    int m0 = blockIdx.y * 64, n0 = blockIdx.x * 64;
    int kz = blockIdx.z;
    int K = (int)gridDim.z * K4;
    int kbeg = kz * K4, kend = kbeg + K4;
    int lr = tid >> 2;
    int lc = (tid & 3) * 4;
    int br = tid >> 4;
    int bc = (tid & 15) * 4;
    float acc[4][4] = {};
    for (int k0 = kbeg; k0 < kend; k0 += 16) {
        float4 av = *(const float4*)(A + (size_t)(m0 + lr) * K + k0 + lc);
        float4 bv = *(const float4*)(B + (size_t)(k0 + br) * N + n0 + bc);
        As[lc + 0][lr] = av.x; As[lc + 1][lr] = av.y; As[lc + 2][lr] = av.z; As[lc + 3][lr] = av.w;
        *(float4*)&Bs[br][bc] = bv;
        __syncthreads();
#pragma unroll
        for (int kk = 0; kk < 16; ++kk) {
            float4 a4 = *(const float4*)&As[kk][ty * 4];
            float4 b4 = *(const float4*)&Bs[kk][tx * 4];
            float aa[4] = {a4.x, a4.y, a4.z, a4.w};
            float bb[4] = {b4.x, b4.y, b4.z, b4.w};
#pragma unroll
            for (int i = 0; i < 4; ++i)
#pragma unroll
                for (int j = 0; j < 4; ++j) acc[i][j] += aa[i] * bb[j];
        }
        __syncthreads();
    }
    float* Cz = Cpart + (size_t)kz * M * N;
#pragma unroll
    for (int i = 0; i < 4; ++i) {
        int m = m0 + ty * 4 + i;
#pragma unroll
        for (int j = 0; j < 4; ++j) {
            int n = n0 + tx * 4 + j;
            Cz[(size_t)m * N + n] = acc[i][j];
        }
    }
}

// ---------------- finishers ----------------
__global__ void attn_fin(const float* __restrict__ Cp, const float* __restrict__ Zr,
                         float* __restrict__ C, int MN, int N) {
    int idx = blockIdx.x * 256 + threadIdx.x;
    float v = Cp[idx] + Cp[MN + idx] + Cp[2 * MN + idx] + Cp[3 * MN + idx];
    v /= Zr[idx / N];
    C[idx] = v > 0.f ? v : (__expf(v) - 1.f);
}

__global__ void sum4_fin(const float* __restrict__ Cp, float* __restrict__ C, int MN) {
    int idx = blockIdx.x * 256 + threadIdx.x;
    C[idx] = Cp[idx] + Cp[MN + idx] + Cp[2 * MN + idx] + Cp[3 * MN + idx];
}

// ---------------- BiLSTM recurrent scan: LDS weights + pure-atomic 64-bit exchange ---
// Round-13 protocol (timed-best 6757us, placement-independent): all exchange traffic
// agent-scope atomic at the LLC. Publisher = wave 0 lanes 0..15 (packs two tagged
// words per 64-bit store, even lanes store). Pollers = waves 1..2 ONLY (different
// waves from publisher -> publisher always progresses). 120 pollers x one 64-bit
// atomic load each. Word = (bf16(h)<<16 | steptag); pair written by ONE store.
// Parity double-buffer; ABA-safe by value dependence; pub memset per launch.
// NEW vs r13: dot-phase remap (rp=tid>>3, k8=tid&7) puts a row's 8 k-partials in 8
// adjacent lanes -> 3x shfl_xor in-wave reduce -> zred[64]; gate phase reads 4 floats
// instead of 32. hbuf padded to 36 floats/chunk so the remapped h-reads tile all 32
// banks conflict-free (same-k8 lane groups broadcast).
__global__ __launch_bounds__(256) void lstm_lds(const float* __restrict__ xin_f,
                                                const float* __restrict__ xin_b,
                                                const float* __restrict__ whh_f,
                                                const float* __restrict__ whh_b,
                                                const float* __restrict__ hc,
                                                float* __restrict__ out,
                                                unsigned int* pubu, int tagbase) {
    int raw = blockIdx.x;
    int lane7 = raw & 7;
    if (lane7 > 1) return;           // 96 dummy blocks exit
    int dir = lane7;
    int b = raw >> 3;                // 0..15
    const float* xin = dir ? xin_b : xin_f;
    const float* whh = dir ? whh_b : whh_f;

    int tid = threadIdx.x;

    __shared__ uint4 W4[2048];                    // 32KB bf16 weights
    __shared__ __align__(16) float hbuf[288];     // 8 chunks x 36 floats (padded)
    __shared__ float zred[64];                    // reduced z per gate row

    // ---- one-time weight staging, packed for wave-linear consumption ----
    for (int idx = tid; idx < 2048; idx += 256) {
        int wave = idx >> 9;
        int i = (idx >> 6) & 7;
        int l = idx & 63;
        int towner = wave * 64 + l;
        int rp = towner >> 3;          // NEW mapping: row-pair = tid>>3
        int k8 = towner & 7;           // NEW mapping: k-chunk = tid&7
        int rloc = 2 * rp + (i >> 2);
        int ii = i & 3;
        int g = rloc >> 4, j = rloc & 15;
        const float* wr = whh + (size_t)(g * HID + b * NU + j) * HID + k8 * 32 + ii * 8;
        uint4 v;
        v.x = bfp(wr[0]) | (bfp(wr[1]) << 16);
        v.y = bfp(wr[2]) | (bfp(wr[3]) << 16);
        v.z = bfp(wr[4]) | (bfp(wr[5]) << 16);
        v.w = bfp(wr[6]) | (bfp(wr[7]) << 16);
        W4[wave * 512 + i * 64 + l] = v;
    }

    if (tid < 256) hbuf[HIDX(tid)] = hc[dir * 512 + tid];
    float c = 0.f;
    float xq0 = 0.f, xq1 = 0.f, xq2 = 0.f, xq3 = 0.f;
    if (tid < 16) {
        c = hc[dir * 512 + 256 + b * NU + tid];
        int t0 = dir ? (SEQL - 1) : 0;
        const float* xr = xin + (size_t)t0 * G4 + b * NU + tid;
        xq0 = xr[0]; xq1 = xr[256]; xq2 = xr[512]; xq3 = xr[768];
    }
    __syncthreads();

    int rp = tid >> 3;                 // row-pair 0..31
    int k8 = tid & 7;                  // k-chunk 0..7 (adjacent lanes)
    int wbase = (tid >> 6) * 512 + (tid & 63);

    // poller mapping: tid 64..183 -> one of 120 partner unit-pairs
    int ppair = tid - 64;
    int upair = (ppair < b * 8) ? ppair : ppair + 8;

    for (int s = 0; s < SEQL; ++s) {
        // ---- dot phase: all 256 threads ----
        const float4* hp = (const float4*)(hbuf + k8 * 36);
        float acc0 = 0.f, acc1 = 0.f;
#pragma unroll
        for (int i = 0; i < 4; ++i) {
            uint4 w0 = W4[wbase + i * 64];
            uint4 w1 = W4[wbase + (i + 4) * 64];
            float4 hA = hp[i * 2];
            float4 hB = hp[i * 2 + 1];
            acc0 += bflo(w0.x) * hA.x + bfhi(w0.x) * hA.y + bflo(w0.y) * hA.z + bfhi(w0.y) * hA.w
                  + bflo(w0.z) * hB.x + bfhi(w0.z) * hB.y + bflo(w0.w) * hB.z + bfhi(w0.w) * hB.w;
            acc1 += bflo(w1.x) * hA.x + bfhi(w1.x) * hA.y + bflo(w1.y) * hA.z + bfhi(w1.y) * hA.w
                  + bflo(w1.z) * hB.x + bfhi(w1.z) * hB.y + bflo(w1.w) * hB.z + bfhi(w1.w) * hB.w;
        }
        // in-wave butterfly over the 8-lane k-group
        acc0 += __shfl_xor(acc0, 1, 64); acc1 += __shfl_xor(acc1, 1, 64);
        acc0 += __shfl_xor(acc0, 2, 64); acc1 += __shfl_xor(acc1, 2, 64);
        acc0 += __shfl_xor(acc0, 4, 64); acc1 += __shfl_xor(acc1, 4, 64);
        if (k8 == 0) {
            zred[2 * rp] = acc0;
            zred[2 * rp + 1] = acc1;
        }
        __syncthreads();

        int t = dir ? (SEQL - 1 - s) : s;
        unsigned int etag = (unsigned int)(tagbase + s + 1) & 0xFFFFu;
        unsigned int* slot = pubu + (((s + 1) & 1) * 2 + dir) * 256;

        if (tid < 16) {
            // ---- gate phase + 64-bit packed publish (wave 0) ----
            float zi = xq0 + zred[tid];
            float zf = xq1 + zred[16 + tid];
            float zg = xq2 + zred[32 + tid];
            float zo = xq3 + zred[48 + tid];
            float ig = sigf(zi), fg = sigf(zf), gt = tanhfast(zg), og = sigf(zo);
            c = fg * c + ig * gt;
            float hn = og * tanhfast(c);
            int u = b * NU + tid;
            hbuf[HIDX(u)] = hn;
            unsigned int word = (bfp(hn) << 16) | etag;
            unsigned int wnext = __shfl_down(word, 1, 64);
            if ((tid & 1) == 0) {
                unsigned long long w64 = (unsigned long long)word |
                                         ((unsigned long long)wnext << 32);
                __hip_atomic_store((unsigned long long*)&slot[u], w64,
                                   __ATOMIC_RELAXED, __HIP_MEMORY_SCOPE_AGENT);
            }
            out[(size_t)t * HCAT + dir * HID + u] = hn;
            // prefetch next x
            if (s + 1 < SEQL) {
                int tn = dir ? (SEQL - 2 - s) : (s + 1);
                const float* xr = xin + (size_t)tn * G4 + b * NU + tid;
                xq0 = xr[0]; xq1 = xr[256]; xq2 = xr[512]; xq3 = xr[768];
            }
        } else if (tid >= 64 && tid < 184 && s + 1 < SEQL) {
            // ---- poll phase: waves 1..2, one 64-bit atomic load per thread ----
            unsigned long long v;
            for (;;) {
                v = __hip_atomic_load((unsigned long long*)&slot[upair * 2],
                                      __ATOMIC_RELAXED, __HIP_MEMORY_SCOPE_AGENT);
                if ((unsigned int)(v & 0xFFFFu) == etag &&
                    (unsigned int)((v >> 32) & 0xFFFFu) == etag) break;
            }
            hbuf[HIDX(upair * 2)]     = bfhi((unsigned int)v);
            hbuf[HIDX(upair * 2 + 1)] = bfhi((unsigned int)(v >> 32));
        }
        __syncthreads();
    }
}

// ---------------- GAT helpers ----------------
__global__ void gat_scores(const float* __restrict__ Wh, const float* __restrict__ a,
                           float* __restrict__ s1, float* __restrict__ s2) {
    int i = blockIdx.x;
    int lane = threadIdx.x;  // 64
    const float* rowp = Wh + (size_t)i * HCAT;
    float p1 = 0.f, p2 = 0.f;
    for (int k = lane; k < HCAT; k += 64) {
        float w = rowp[k];
        p1 += w * a[k];
        p2 += w * a[HCAT + k];
    }
    for (int off = 32; off; off >>= 1) {
        p1 += __shfl_down(p1, off, 64);
        p2 += __shfl_down(p2, off, 64);
    }
    if (lane == 0) { s1[i] = p1; s2[i] = p2; }
}

__global__ void reduce_max_k(const float* __restrict__ s2, float* __restrict__ outv) {
    __shared__ float red[256];
    int tid = threadIdx.x;
    float m = -INFINITY;
    for (int k = tid; k < SEQL; k += 256) m = fmaxf(m, s2[k]);
    red[tid] = m;
    __syncthreads();
    for (int off = 128; off; off >>= 1) {
        if (tid < off) red[tid] = fmaxf(red[tid], red[tid + off]);
        __syncthreads();
    }
    if (tid == 0) outv[0] = red[0];
}

__global__ void gat_p(const float* __restrict__ s1, const float* __restrict__ s2,
                      const float* __restrict__ s2m, float* __restrict__ P,
                      float* __restrict__ Z) {
    int i = blockIdx.x;
    int tid = threadIdx.x;  // 256
    float base = s1[i];
    float m = base + s2m[0];
    m = m > 0.f ? m : ALPHA_LR * m;  // leaky_relu monotonic -> exact row max
    float zs = 0.f;
    for (int jj = tid; jj < SEQL; jj += 256) {
        float e = base + s2[jj];
        e = e > 0.f ? e : ALPHA_LR * e;
        float p = __expf(e - m);
        P[(size_t)i * SEQL + jj] = p;
        zs += p;
    }
    __shared__ float red[256];
    red[tid] = zs;
    __syncthreads();
    for (int off = 128; off; off >>= 1) {
        if (tid < off) red[tid] += red[tid + off];
        __syncthreads();
    }
    if (tid == 0) Z[i] = red[0];
}

// ---------------- Viterbi (max-plus parallel scan) ----------------
__global__ void vit_chunkA(const float* __restrict__ feats, const float* __restrict__ trans,
                           float* __restrict__ chunkA) {
    int c = blockIdx.x;
    int tid = threadIdx.x;  // 128
    __shared__ float Acur[121], tr[121];
    if (tid < 121) tr[tid] = trans[tid];
    __syncthreads();
    int n = tid / 11, p = tid % 11;
    int t0 = c * VCS;
    if (tid < 121) Acur[tid] = tr[tid] + feats[t0 * TT + n];
    __syncthreads();
    for (int t = t0 + 1; t < t0 + VCS; ++t) {
        float v = -INFINITY;
        if (tid < 121) {
            float ft = feats[t * TT + n];
#pragma unroll
            for (int k = 0; k < 11; ++k) v = fmaxf(v, tr[n * 11 + k] + Acur[k * 11 + p]);
            v += ft;
        }
        __syncthreads();
        if (tid < 121) Acur[tid] = v;
        __syncthreads();
    }
    if (tid < 121) chunkA[c * 121 + tid] = Acur[tid];
}

__global__ void vit_prefix(const float* __restrict__ chunkA, float* __restrict__ fvstart) {
    int tid = threadIdx.x;  // 128
    __shared__ float fv[11];
    if (tid < 11) fv[tid] = (tid == START_TAG) ? 0.f : NEGV;
    __syncthreads();
    if (tid < 11) fvstart[tid] = fv[tid];
    for (int c = 0; c < VCH; ++c) {
        float v = -INFINITY;
        if (tid < 11) {
            for (int p = 0; p < 11; ++p) v = fmaxf(v, chunkA[c * 121 + tid * 11 + p] + fv[p]);
        }
        __syncthreads();
        if (tid < 11) { fv[tid] = v; fvstart[(c + 1) * TT + tid] = v; }
        __syncthreads();
    }
}

__global__ void vit_chunkC(const float* __restrict__ feats, const float* __restrict__ trans,
                           const float* __restrict__ fvstart, int* __restrict__ bp,
                           float* __restrict__ fvfinal) {
    int c = blockIdx.x;
    int tid = threadIdx.x;  // 128
    __shared__ float fv[11], tr[121], sc[121], mx[11];
    if (tid < 121) tr[tid] = trans[tid];
    if (tid < 11) fv[tid] = fvstart[c * TT + tid];
    __syncthreads();
    int t0 = c * VCS;
    for (int t = t0; t < t0 + VCS; ++t) {
        if (tid < 121) sc[tid] = fv[tid % 11] + tr[tid];
        __syncthreads();
        if (tid < 11) {
            float best = -INFINITY;
            int bi = 0;
            for (int k = 0; k < 11; ++k) {
                float v = sc[tid * 11 + k];
                if (v > best) { best = v; bi = k; }
            }
            bp[t * TT + tid] = bi;
            mx[tid] = best + feats[t * TT + tid];
        }
        __syncthreads();
        if (tid < 11) fv[tid] = mx[tid];
        __syncthreads();
    }
    if (c == VCH - 1 && tid < 11) fvfinal[tid] = fv[tid];
}

__global__ __launch_bounds__(1024) void vit_back(const int* __restrict__ bp,
                                                 const float* __restrict__ fvfinal,
                                                 const float* __restrict__ trans,
                                                 float* __restrict__ outp) {
    __shared__ unsigned char bufA[SEQL * TT];
    __shared__ unsigned char bufB[SEQL * TT];
    __shared__ int bestIdx;
    int tid = threadIdx.x;
    for (int idx = tid; idx < SEQL * TT; idx += 1024) {
        int t = idx / TT, n = idx - t * TT;
        bufA[idx] = (t < SEQL - 1) ? (unsigned char)bp[(t + 1) * TT + n] : (unsigned char)n;
    }
    __syncthreads();
    unsigned char* a = bufA;
    unsigned char* b = bufB;
    for (int len = 1; len < SEQL - 1; len <<= 1) {
        for (int idx = tid; idx < SEQL * TT; idx += 1024) {
            int t = idx / TT, n = idx - t * TT;
            int m = (t + len <= SEQL - 1) ? (int)a[(t + len) * TT + n] : n;
            b[t * TT + n] = a[t * TT + m];
        }
        __syncthreads();
        unsigned char* tmp = a; a = b; b = tmp;
        __syncthreads();
    }
    if (tid == 0) {
        float bs = -INFINITY;
        int bi = 0;
        for (int p = 0; p < 11; ++p) {
            float v = fvfinal[p] + trans[STOP_TAG * 11 + p];
            if (v > bs) { bs = v; bi = p; }
        }
        outp[0] = bs;
        bestIdx = bi;
    }
    __syncthreads();
    int best = bestIdx;
    for (int t = tid; t < SEQL; t += 1024) outp[1 + t] = (float)a[t * TT + best];
}

// ---------------- host launcher ----------------
extern "C" void kernel_launch(void* const* d_in, const int* in_sizes, int n_in,
                              void* d_out, int out_size, void* d_ws, size_t ws_size,
                              hipStream_t stream) {
    const int* sent = (const int*)d_in[0];
    const float* emb = (const float*)d_in[1];
    const float* w1f = (const float*)d_in[2];
    const float* u1f = (const float*)d_in[3];
    const float* b1f = (const float*)d_in[4];
    const float* w1b = (const float*)d_in[5];
    const float* u1b = (const float*)d_in[6];
    const float* b1b = (const float*)d_in[7];
    const float* hc1 = (const float*)d_in[8];
    const float* g1W = (const float*)d_in[9];
    const float* g1a = (const float*)d_in[10];
    const float* g2W = (const float*)d_in[11];
    const float* g2a = (const float*)d_in[12];
    const float* w2f = (const float*)d_in[13];
    const float* u2f = (const float*)d_in[14];
    const float* b2f = (const float*)d_in[15];
    const float* w2b = (const float*)d_in[16];
    const float* u2b = (const float*)d_in[17];
    const float* b2b = (const float*)d_in[18];
    const float* hc2 = (const float*)d_in[19];
    const float* wtag = (const float*)d_in[20];
    const float* btag = (const float*)d_in[21];
    const float* trans = (const float*)d_in[22];

    float* ws = (float*)d_ws;
    float* x = ws;                      // 524288
    float* R1 = x + 524288;             // 4194304 floats (xin_f+xin_b | P)
    float* xin_f = R1;
    float* xin_b = R1 + 2097152;
    float* P = R1;
    float* h1cat = R1 + 4194304;        // 1048576 (h1cat | g2)
    float* Wh = h1cat + 1048576;        // 1048576
    float* g1 = Wh + 1048576;           // 1048576 (g1 | h2cat)
    float* s1 = g1 + 1048576;           // 2048
    float* s2 = s1 + 2048;              // 2048
    float* Zr = s2 + 2048;              // 2048
    float* s2m = Zr + 2048;             // 16
    unsigned int* pub = (unsigned int*)(s2m + 16);  // 1024 u32 (8B-aligned)
    float* feats = (float*)(pub + 1024);            // 22528
    float* chA = feats + 22528;         // 7744
    float* fvst = chA + 7744;           // 720
    float* fvfin = fvst + 720;          // 16
    int* bp = (int*)(fvfin + 16);       // 22528 ints
    float* Cpart = (float*)(bp + 22528); // 4x1048576 floats (16MB)

    hipMemsetAsync(pub, 0, 1024 * sizeof(unsigned int), stream);

    embed_k<<<SEQL, 256, 0, stream>>>(sent, emb, x);

    // BiLSTM 1 input projections
    gemm_nt<<<dim3(16, 32), 256, 0, stream>>>(x, w1f, b1f, xin_f, SEQL, G4, EDIM);
    gemm_nt<<<dim3(16, 32), 256, 0, stream>>>(x, w1b, b1b, xin_b, SEQL, G4, EDIM);
    lstm_lds<<<128, 256, 0, stream>>>(xin_f, xin_b, u1f, u1b, hc1, h1cat, pub, 0);

    // GAT 1 (both GEMMs K-split x4 for occupancy)
    gemm_nn_ks<<<dim3(8, 32, 4), 256, 0, stream>>>(h1cat, g1W, Cpart, SEQL, HCAT, HCAT / 4);
    sum4_fin<<<4096, 256, 0, stream>>>(Cpart, Wh, SEQL * HCAT);
    gat_scores<<<SEQL, 64, 0, stream>>>(Wh, g1a, s1, s2);
    reduce_max_k<<<1, 256, 0, stream>>>(s2, s2m);
    gat_p<<<SEQL, 256, 0, stream>>>(s1, s2, s2m, P, Zr);
    gemm_nn_ks<<<dim3(8, 32, 4), 256, 0, stream>>>(P, Wh, Cpart, SEQL, HCAT, SEQL / 4);
    attn_fin<<<4096, 256, 0, stream>>>(Cpart, Zr, g1, SEQL * HCAT, HCAT);

    // GAT 2
    gemm_nn_ks<<<dim3(8, 32, 4), 256, 0, stream>>>(g1, g2W, Cpart, SEQL, HCAT, HCAT / 4);
    sum4_fin<<<4096, 256, 0, stream>>>(Cpart, Wh, SEQL * HCAT);
    gat_scores<<<SEQL, 64, 0, stream>>>(Wh, g2a, s1, s2);
    reduce_max_k<<<1, 256, 0, stream>>>(s2, s2m);
    gat_p<<<SEQL, 256, 0, stream>>>(s1, s2, s2m, P, Zr);
    float* g2v = h1cat;  // reuse
    gemm_nn_ks<<<dim3(8, 32, 4), 256, 0, stream>>>(P, Wh, Cpart, SEQL, HCAT, SEQL / 4);
    attn_fin<<<4096, 256, 0, stream>>>(Cpart, Zr, g2v, SEQL * HCAT, HCAT);

    // BiLSTM 2
    gemm_nt<<<dim3(16, 32), 256, 0, stream>>>(g2v, w2f, b2f, xin_f, SEQL, G4, HCAT);
    gemm_nt<<<dim3(16, 32), 256, 0, stream>>>(g2v, w2b, b2b, xin_b, SEQL, G4, HCAT);
    float* h2cat = g1;  // reuse
    lstm_lds<<<128, 256, 0, stream>>>(xin_f, xin_b, u2f, u2b, hc2, h2cat, pub, 2048);

    // tag projection + Viterbi
    gemm_nt<<<dim3(1, 32), 256, 0, stream>>>(h2cat, wtag, btag, feats, SEQL, TT, HCAT);
    vit_chunkA<<<VCH, 128, 0, stream>>>(feats, trans, chA);
    vit_prefix<<<1, 128, 0, stream>>>(chA, fvst);
    vit_chunkC<<<VCH, 128, 0, stream>>>(feats, trans, fvst, bp, fvfin);
    vit_back<<<1, 1024, 0, stream>>>(bp, fvfin, trans, (float*)d_out);
}